// Round 5
// baseline (132.340 us; speedup 1.0000x reference)
//
#include <hip/hip_runtime.h>

// VQ: x (16,64,64,64) f32, codebook e (64,1024) f32. N=65536, D=64, K=1024.
//
// R11: vq_main pinned at 52.5us across THREE structures (R6 direct-L2 8w/CU,
// R7 direct-L2 16w/CU, R10 LDS-shared) => per-wave instruction stream is the
// binding constraint (likely at DVFS-reduced clock); occupancy/traffic are
// not. Attack the OTHER 78us instead: inline the exact fallback into
// vq_main and delete the 3rd kernel + launch + global worklist round-trip.
//  - certification pushes to a block-local LDS worklist (each block owns its
//    128 positions); block then resolves each ambiguous position with the
//    bit-exact np scan (VERBATIM vq_fallback math: register-cached x,
//    pairwise-8 Ap, sequential-k FMA chain, same tie-breaks), writing the
//    exact index into bk_lds BEFORE the single STE write phase. No overwrite
//    pass, no cross-block interaction.
//  - main tile loop = R10-verbatim (register-staged LDS double buffer,
//    3-term split-bf16, m = x.e - 0.5*c2 via acc-init, argMAX,
//    certify iff m1-m2 > MARGIN/2). Proven absmax 0.

#define D 64
#define K 1024
#define NPOS 65536
#define HW 4096
#define XSTRIDE 262144  // D*HW
#define MARGIN 1.0e-3f

typedef float vfloat4 __attribute__((ext_vector_type(4)));
typedef short short8  __attribute__((ext_vector_type(8)));

static __device__ __forceinline__ unsigned short bf16_rne(float f) {
    unsigned u = __float_as_uint(f);
    u += 0x7FFFu + ((u >> 16) & 1u);
    return (unsigned short)(u >> 16);
}
static __device__ __forceinline__ float bf16_to_f32(unsigned short h) {
    return __uint_as_float(((unsigned)h) << 16);
}

// ---- prep: codebook -> bf16 split B-fragments + c2n = -0.5*sum(e^2) -------
// frag layout: ebf[tile][s][split][lane][j], lane=q*16+n, value =
// split(e[d][k]), d=s*32+q*8+j, k=tile*16+n. Thread t of the main kernel
// owns 16B at t*16 within a tile: stage load + ds_write are linear copies.
__global__ void vq_prep(const float* __restrict__ e,
                        unsigned short* __restrict__ ebf,
                        float* __restrict__ c2n) {
    const int tile = blockIdx.x;               // 0..63
    const int t = threadIdx.x;
    const int n = t & 15;
    const int dg = t >> 4;                     // 0..15
#pragma unroll
    for (int i = 0; i < 4; ++i) {
        const int d = dg * 4 + i;
        const float v = e[d * K + tile * 16 + n];
        const unsigned short hh = bf16_rne(v);
        const float rem = v - bf16_to_f32(hh);     // exact (Sterbenz)
        const unsigned short hl = bf16_rne(rem);
        const int s = d >> 5, q = (d >> 3) & 3, j = d & 7;
        const int lanei = q * 16 + n;
        ebf[(((tile * 2 + s) * 2 + 0) * 64 + lanei) * 8 + j] = hh;
        ebf[(((tile * 2 + s) * 2 + 1) * 64 + lanei) * 8 + j] = hl;
    }
    if (t < 16) {
        const int k = tile * 16 + t;
        float s = 0.f;
#pragma unroll
        for (int d = 0; d < D; ++d) {
            const float v = e[d * K + k];      // sequential-d rounded squares
            s = s + __fmul_rn(v, v);
        }
        c2n[k] = -0.5f * s;
    }
}

// ---- main: 512 blocks x 256 threads; block = 128 positions, 4 waves -------
// Tile loop + certify as R10; then in-block exact resolve of ambiguous
// positions; then one STE write phase for all 128 positions.
__global__ __launch_bounds__(256, 2)
void vq_main(const float* __restrict__ x, const float* __restrict__ e,
             const unsigned short* __restrict__ ebf,
             const float* __restrict__ c2n,
             float* __restrict__ out) {
    __shared__ __align__(16) unsigned short lds_e[2][2048];  // 2 x 4 KB tiles
    __shared__ int   bk_lds[128];
    __shared__ int   lwl[128];
    __shared__ int   lwl_count;
    __shared__ float rs[256];
    __shared__ int   rk[256];
    const int t = threadIdx.x;
    const int lane = t & 63;
    const int w = t >> 6;                      // wave 0..3 = position group
    const int p0 = blockIdx.x * 128;
    const int b = p0 >> 12;                    // 128 | 4096 -> single b
    const int sp0 = p0 & (HW - 1);
    const int n = lane & 15;                   // A-row m / B-col n / C col
    const int q = lane >> 4;                   // k-quad / C row group

    if (t == 0) lwl_count = 0;

    // A-frags (registers): xh/xl for 2 M-tiles x 2 K-steps
    short8 ah[2][2], al[2][2];
#pragma unroll
    for (int mt = 0; mt < 2; ++mt) {
        const int spc = sp0 + w * 32 + mt * 16 + n;
#pragma unroll
        for (int s = 0; s < 2; ++s) {
            short8 fh, fl_;
#pragma unroll
            for (int j = 0; j < 8; ++j) {
                const int d = s * 32 + q * 8 + j;      // A[m=n][k=q*8+j]
                const float v = x[(size_t)b * XSTRIDE + (size_t)d * HW + spc];
                const unsigned short h = bf16_rne(v);
                fh[j] = (short)h;
                fl_[j] = (short)bf16_rne(v - bf16_to_f32(h));
            }
            ah[mt][s] = fh; al[mt][s] = fl_;
        }
    }

    // stage tile 0: global -> reg -> LDS (thread t owns 16B at t*16)
    {
        const short8 stg = *(const short8*)(ebf + t * 8);
        *(short8*)(&lds_e[0][t * 8]) = stg;
    }

    float s1[2][4], s2[2][4]; int t1[2][4];
#pragma unroll
    for (int mt = 0; mt < 2; ++mt)
#pragma unroll
        for (int r = 0; r < 4; ++r) { s1[mt][r] = -3.4e38f; s2[mt][r] = -3.4e38f; t1[mt][r] = 0; }

    __syncthreads();                           // tile 0 in LDS + lwl_count=0

    for (int tt = 0; tt < 64; ++tt) {
        const int cur = tt & 1;
        short8 stg;
        if (tt < 63)                           // issue early: hide L2 latency
            stg = *(const short8*)(ebf + (size_t)(tt + 1) * 2048 + t * 8);
        const short8* fb = (const short8*)(&lds_e[cur][0]);
        const short8 bh0 = fb[lane];           // s0 hi
        const short8 bl0 = fb[64 + lane];      // s0 lo
        const short8 bh1 = fb[128 + lane];     // s1 hi
        const short8 bl1 = fb[192 + lane];     // s1 lo
        const float c2v = c2n[tt * 16 + n];
#pragma unroll
        for (int mt = 0; mt < 2; ++mt) {
            vfloat4 acc = {c2v, c2v, c2v, c2v};    // m = x.e - 0.5*c2
            acc = __builtin_amdgcn_mfma_f32_16x16x32_bf16(ah[mt][0], bh0, acc, 0, 0, 0);
            acc = __builtin_amdgcn_mfma_f32_16x16x32_bf16(ah[mt][1], bh1, acc, 0, 0, 0);
            acc = __builtin_amdgcn_mfma_f32_16x16x32_bf16(al[mt][0], bh0, acc, 0, 0, 0);
            acc = __builtin_amdgcn_mfma_f32_16x16x32_bf16(al[mt][1], bh1, acc, 0, 0, 0);
            acc = __builtin_amdgcn_mfma_f32_16x16x32_bf16(ah[mt][0], bl0, acc, 0, 0, 0);
            acc = __builtin_amdgcn_mfma_f32_16x16x32_bf16(ah[mt][1], bl1, acc, 0, 0, 0);
#pragma unroll
            for (int r = 0; r < 4; ++r) {      // C/D: row=q*4+r, col=n; argMAX
                const float m = acc[r];
                const bool gt = m > s1[mt][r];
                s2[mt][r] = fmaxf(s2[mt][r], fminf(m, s1[mt][r]));
                s1[mt][r] = gt ? m : s1[mt][r];
                t1[mt][r] = gt ? tt : t1[mt][r];
            }
        }
        if (tt < 63)                           // reg dep forces vmcnt wait
            *(short8*)(&lds_e[cur ^ 1][t * 8]) = stg;
        __syncthreads();                       // ds_write visible to all waves
    }

    // merge top-2 across the 16 code-columns; certify; push LOCAL worklist
#pragma unroll
    for (int mt = 0; mt < 2; ++mt)
#pragma unroll
        for (int r = 0; r < 4; ++r) {
            float a1 = s1[mt][r], a2 = s2[mt][r];
            int ak = t1[mt][r] * 16 + n;
#pragma unroll
            for (int m = 1; m < 16; m <<= 1) {
                const float o1 = __shfl_xor(a1, m, 64);
                const float o2 = __shfl_xor(a2, m, 64);
                const int   ok = __shfl_xor(ak, m, 64);
                const bool take = (o1 > a1) || (o1 == a1 && ok < ak);
                const float loser = take ? a1 : o1;
                a1 = take ? o1 : a1;
                ak = take ? ok : ak;
                a2 = fmaxf(fmaxf(a2, o2), loser);
            }
            if (n == 0) {
                const int pl = w * 32 + mt * 16 + q * 4 + r;
                bk_lds[pl] = ak;
                if (a1 - a2 <= 0.5f * MARGIN) {   // score gap = 2*(m1-m2)
                    const int idx = atomicAdd(&lwl_count, 1);
                    lwl[idx] = pl;
                }
            }
        }
    __syncthreads();

    // in-block exact resolve (bit-exact np scan, verbatim fallback math)
    const int cnt = lwl_count;                 // uniform after barrier
    for (int i = 0; i < cnt; ++i) {
        const int pl = lwl[i];
        const int sp = sp0 + pl;
        float xv[D];                           // broadcast loads, L1-hot
#pragma unroll
        for (int d = 0; d < D; ++d)
            xv[d] = x[(size_t)b * XSTRIDE + (size_t)d * HW + sp];
        // Ap = np.sum(x**2) in numpy pairwise-8 order (verified grouping)
        float r8[8];
#pragma unroll
        for (int i0 = 0; i0 < 8; ++i0) r8[i0] = __fmul_rn(xv[i0], xv[i0]);
#pragma unroll
        for (int j = 1; j < 8; ++j)
#pragma unroll
            for (int i0 = 0; i0 < 8; ++i0)
                r8[i0] = r8[i0] + __fmul_rn(xv[8 * j + i0], xv[8 * j + i0]);
        const float Ap = ((r8[0] + r8[1]) + (r8[2] + r8[3])) + ((r8[4] + r8[5]) + (r8[6] + r8[7]));
        float bs = 3.4e38f; int bk = 0x7fffffff;
#pragma unroll
        for (int j = 0; j < 4; ++j) {
            const int k = t + 256 * j;         // ascending k per thread
            float acc = 0.f;
#pragma unroll
            for (int d = 0; d < D; ++d)        // sequential-k FMA chain (np)
                acc = __builtin_fmaf(xv[d], e[d * K + k], acc);
            const float c2k = -2.0f * c2n[k];  // exact pow2 scale = np c2[k]
            const float sc = __builtin_fmaf(-2.f, acc, Ap) + c2k;
            if (sc < bs || (sc == bs && k < bk)) { bs = sc; bk = k; }
        }
        rs[t] = bs; rk[t] = bk;
        __syncthreads();
        for (int off = 128; off > 0; off >>= 1) {
            if (t < off) {
                const float so = rs[t + off]; const int ko = rk[t + off];
                if (so < rs[t] || (so == rs[t] && ko < rk[t])) { rs[t] = so; rk[t] = ko; }
            }
            __syncthreads();
        }
        if (t == 0) bk_lds[pl] = rk[0];        // exact index replaces approx
        __syncthreads();
    }

    // single STE write phase: 128 positions x 64 channels
    const int pl = t & 127;
    const int half = t >> 7;
    const int bk = bk_lds[pl];
    const int sp = sp0 + pl;
    const float* xb = x + (size_t)b * XSTRIDE + sp;
    float* ob = out + (size_t)b * XSTRIDE + sp;
#pragma unroll
    for (int i = 0; i < 32; ++i) {
        const int c = half * 32 + i;
        const float xq = xb[(size_t)c * HW];
        const float qv = e[c * K + bk];
        ob[(size_t)c * HW] = xq + (qv - xq);   // np STE: fl(x + fl(q-x))
    }
}

extern "C" void kernel_launch(void* const* d_in, const int* in_sizes, int n_in,
                              void* d_out, int out_size, void* d_ws, size_t ws_size,
                              hipStream_t stream) {
    const float* x = (const float*)d_in[0];
    const float* e = (const float*)d_in[1];
    float* out = (float*)d_out;

    char* ws = (char*)d_ws;                          // ~260 KB used
    unsigned short* ebf = (unsigned short*)ws;       // 256 KB B-fragments
    float* c2n = (float*)(ws + 262144);              // 4 KB  (-0.5*sum e^2)

    vq_prep<<<64, 256, 0, stream>>>(e, ebf, c2n);
    vq_main<<<NPOS / 128, 256, 0, stream>>>(x, e, ebf, c2n, out);
}

// Round 6
// 129.046 us; speedup vs baseline: 1.0255x; 1.0255x over previous
//
#include <hip/hip_runtime.h>

// VQ: x (16,64,64,64) f32, codebook e (64,1024) f32. N=65536, D=64, K=1024.
//
// R12: R11 post-mortem: inlined resolve was ~free, but its xv[64] register
// cache ballooned VGPR 48->128 => occupancy 19.5->14.3% => the UNCHANGED
// tile loop slowed 52.5->72.6us (ratio matches occupancy ratio). Fix: keep
// the 2-kernel structure (R11's real win: fallback kernel+launch deleted),
// make the resolve VGPR-neutral:
//  - x for the ambiguous position goes to LDS (xlds[64], broadcast reads)
//    instead of 64 VGPRs;
//  - resolve d-loop unroll capped at 8 (bounds in-flight e-loads; FMA chain
//    order d=0..63 unchanged => bit-exact).
// Everything else R11-verbatim: register-staged LDS double-buffered tile
// loop, 3-term split-bf16 (xh*eh + xl*eh + xh*el), m = x.e - 0.5*c2 via
// acc-init, argMAX, certify iff m1-m2 > MARGIN/2, block-local worklist,
// bit-exact np scan resolve (pairwise-8 Ap, sequential-k FMA chain, same
// tie-breaks), single STE write phase.

#define D 64
#define K 1024
#define NPOS 65536
#define HW 4096
#define XSTRIDE 262144  // D*HW
#define MARGIN 1.0e-3f

typedef float vfloat4 __attribute__((ext_vector_type(4)));
typedef short short8  __attribute__((ext_vector_type(8)));

static __device__ __forceinline__ unsigned short bf16_rne(float f) {
    unsigned u = __float_as_uint(f);
    u += 0x7FFFu + ((u >> 16) & 1u);
    return (unsigned short)(u >> 16);
}
static __device__ __forceinline__ float bf16_to_f32(unsigned short h) {
    return __uint_as_float(((unsigned)h) << 16);
}

// ---- prep: codebook -> bf16 split B-fragments + c2n = -0.5*sum(e^2) -------
// frag layout: ebf[tile][s][split][lane][j], lane=q*16+n, value =
// split(e[d][k]), d=s*32+q*8+j, k=tile*16+n. Thread t of the main kernel
// owns 16B at t*16 within a tile: stage load + ds_write are linear copies.
__global__ void vq_prep(const float* __restrict__ e,
                        unsigned short* __restrict__ ebf,
                        float* __restrict__ c2n) {
    const int tile = blockIdx.x;               // 0..63
    const int t = threadIdx.x;
    const int n = t & 15;
    const int dg = t >> 4;                     // 0..15
#pragma unroll
    for (int i = 0; i < 4; ++i) {
        const int d = dg * 4 + i;
        const float v = e[d * K + tile * 16 + n];
        const unsigned short hh = bf16_rne(v);
        const float rem = v - bf16_to_f32(hh);     // exact (Sterbenz)
        const unsigned short hl = bf16_rne(rem);
        const int s = d >> 5, q = (d >> 3) & 3, j = d & 7;
        const int lanei = q * 16 + n;
        ebf[(((tile * 2 + s) * 2 + 0) * 64 + lanei) * 8 + j] = hh;
        ebf[(((tile * 2 + s) * 2 + 1) * 64 + lanei) * 8 + j] = hl;
    }
    if (t < 16) {
        const int k = tile * 16 + t;
        float s = 0.f;
#pragma unroll
        for (int d = 0; d < D; ++d) {
            const float v = e[d * K + k];      // sequential-d rounded squares
            s = s + __fmul_rn(v, v);
        }
        c2n[k] = -0.5f * s;
    }
}

// ---- main: 512 blocks x 256 threads; block = 128 positions, 4 waves -------
// Tile loop + certify as R10; in-block exact resolve (LDS-cached x); one STE
// write phase for all 128 positions.
__global__ __launch_bounds__(256, 2)
void vq_main(const float* __restrict__ x, const float* __restrict__ e,
             const unsigned short* __restrict__ ebf,
             const float* __restrict__ c2n,
             float* __restrict__ out) {
    __shared__ __align__(16) unsigned short lds_e[2][2048];  // 2 x 4 KB tiles
    __shared__ int   bk_lds[128];
    __shared__ int   lwl[128];
    __shared__ int   lwl_count;
    __shared__ float rs[256];
    __shared__ int   rk[256];
    __shared__ float xlds[64];
    const int t = threadIdx.x;
    const int lane = t & 63;
    const int w = t >> 6;                      // wave 0..3 = position group
    const int p0 = blockIdx.x * 128;
    const int b = p0 >> 12;                    // 128 | 4096 -> single b
    const int sp0 = p0 & (HW - 1);
    const int n = lane & 15;                   // A-row m / B-col n / C col
    const int q = lane >> 4;                   // k-quad / C row group

    if (t == 0) lwl_count = 0;

    // A-frags (registers): xh/xl for 2 M-tiles x 2 K-steps
    short8 ah[2][2], al[2][2];
#pragma unroll
    for (int mt = 0; mt < 2; ++mt) {
        const int spc = sp0 + w * 32 + mt * 16 + n;
#pragma unroll
        for (int s = 0; s < 2; ++s) {
            short8 fh, fl_;
#pragma unroll
            for (int j = 0; j < 8; ++j) {
                const int d = s * 32 + q * 8 + j;      // A[m=n][k=q*8+j]
                const float v = x[(size_t)b * XSTRIDE + (size_t)d * HW + spc];
                const unsigned short h = bf16_rne(v);
                fh[j] = (short)h;
                fl_[j] = (short)bf16_rne(v - bf16_to_f32(h));
            }
            ah[mt][s] = fh; al[mt][s] = fl_;
        }
    }

    // stage tile 0: global -> reg -> LDS (thread t owns 16B at t*16)
    {
        const short8 stg = *(const short8*)(ebf + t * 8);
        *(short8*)(&lds_e[0][t * 8]) = stg;
    }

    float s1[2][4], s2[2][4]; int t1[2][4];
#pragma unroll
    for (int mt = 0; mt < 2; ++mt)
#pragma unroll
        for (int r = 0; r < 4; ++r) { s1[mt][r] = -3.4e38f; s2[mt][r] = -3.4e38f; t1[mt][r] = 0; }

    __syncthreads();                           // tile 0 in LDS + lwl_count=0

    for (int tt = 0; tt < 64; ++tt) {
        const int cur = tt & 1;
        short8 stg;
        if (tt < 63)                           // issue early: hide L2 latency
            stg = *(const short8*)(ebf + (size_t)(tt + 1) * 2048 + t * 8);
        const short8* fb = (const short8*)(&lds_e[cur][0]);
        const short8 bh0 = fb[lane];           // s0 hi
        const short8 bl0 = fb[64 + lane];      // s0 lo
        const short8 bh1 = fb[128 + lane];     // s1 hi
        const short8 bl1 = fb[192 + lane];     // s1 lo
        const float c2v = c2n[tt * 16 + n];
#pragma unroll
        for (int mt = 0; mt < 2; ++mt) {
            vfloat4 acc = {c2v, c2v, c2v, c2v};    // m = x.e - 0.5*c2
            acc = __builtin_amdgcn_mfma_f32_16x16x32_bf16(ah[mt][0], bh0, acc, 0, 0, 0);
            acc = __builtin_amdgcn_mfma_f32_16x16x32_bf16(ah[mt][1], bh1, acc, 0, 0, 0);
            acc = __builtin_amdgcn_mfma_f32_16x16x32_bf16(al[mt][0], bh0, acc, 0, 0, 0);
            acc = __builtin_amdgcn_mfma_f32_16x16x32_bf16(al[mt][1], bh1, acc, 0, 0, 0);
            acc = __builtin_amdgcn_mfma_f32_16x16x32_bf16(ah[mt][0], bl0, acc, 0, 0, 0);
            acc = __builtin_amdgcn_mfma_f32_16x16x32_bf16(ah[mt][1], bl1, acc, 0, 0, 0);
#pragma unroll
            for (int r = 0; r < 4; ++r) {      // C/D: row=q*4+r, col=n; argMAX
                const float m = acc[r];
                const bool gt = m > s1[mt][r];
                s2[mt][r] = fmaxf(s2[mt][r], fminf(m, s1[mt][r]));
                s1[mt][r] = gt ? m : s1[mt][r];
                t1[mt][r] = gt ? tt : t1[mt][r];
            }
        }
        if (tt < 63)                           // reg dep forces vmcnt wait
            *(short8*)(&lds_e[cur ^ 1][t * 8]) = stg;
        __syncthreads();                       // ds_write visible to all waves
    }

    // merge top-2 across the 16 code-columns; certify; push LOCAL worklist
#pragma unroll
    for (int mt = 0; mt < 2; ++mt)
#pragma unroll
        for (int r = 0; r < 4; ++r) {
            float a1 = s1[mt][r], a2 = s2[mt][r];
            int ak = t1[mt][r] * 16 + n;
#pragma unroll
            for (int m = 1; m < 16; m <<= 1) {
                const float o1 = __shfl_xor(a1, m, 64);
                const float o2 = __shfl_xor(a2, m, 64);
                const int   ok = __shfl_xor(ak, m, 64);
                const bool take = (o1 > a1) || (o1 == a1 && ok < ak);
                const float loser = take ? a1 : o1;
                a1 = take ? o1 : a1;
                ak = take ? ok : ak;
                a2 = fmaxf(fmaxf(a2, o2), loser);
            }
            if (n == 0) {
                const int pl = w * 32 + mt * 16 + q * 4 + r;
                bk_lds[pl] = ak;
                if (a1 - a2 <= 0.5f * MARGIN) {   // score gap = 2*(m1-m2)
                    const int idx = atomicAdd(&lwl_count, 1);
                    lwl[idx] = pl;
                }
            }
        }
    __syncthreads();

    // in-block exact resolve (bit-exact np scan). x goes through LDS
    // (broadcast reads) -- NOT a register array -- to keep VGPR at the tile
    // loop's level; resolve d-loop unroll capped to bound in-flight e-loads.
    const int cnt = lwl_count;                 // uniform after barrier
    for (int i = 0; i < cnt; ++i) {
        const int pl = lwl[i];
        const int sp = sp0 + pl;
        if (t < 64)
            xlds[t] = x[(size_t)b * XSTRIDE + (size_t)t * HW + sp];
        __syncthreads();
        // Ap = np.sum(x**2) in numpy pairwise-8 order (verified grouping)
        float r8[8];
#pragma unroll
        for (int i0 = 0; i0 < 8; ++i0) {
            const float v = xlds[i0];
            r8[i0] = __fmul_rn(v, v);
        }
#pragma unroll
        for (int j = 1; j < 8; ++j)
#pragma unroll
            for (int i0 = 0; i0 < 8; ++i0) {
                const float v = xlds[8 * j + i0];
                r8[i0] = r8[i0] + __fmul_rn(v, v);
            }
        const float Ap = ((r8[0] + r8[1]) + (r8[2] + r8[3])) + ((r8[4] + r8[5]) + (r8[6] + r8[7]));
        float bs = 3.4e38f; int bk = 0x7fffffff;
#pragma unroll
        for (int j = 0; j < 4; ++j) {
            const int k = t + 256 * j;         // ascending k per thread
            float acc = 0.f;
#pragma unroll 8
            for (int d = 0; d < D; ++d)        // sequential-k FMA chain (np)
                acc = __builtin_fmaf(xlds[d], e[d * K + k], acc);
            const float c2k = -2.0f * c2n[k];  // exact pow2 scale = np c2[k]
            const float sc = __builtin_fmaf(-2.f, acc, Ap) + c2k;
            if (sc < bs || (sc == bs && k < bk)) { bs = sc; bk = k; }
        }
        rs[t] = bs; rk[t] = bk;
        __syncthreads();
        for (int off = 128; off > 0; off >>= 1) {
            if (t < off) {
                const float so = rs[t + off]; const int ko = rk[t + off];
                if (so < rs[t] || (so == rs[t] && ko < rk[t])) { rs[t] = so; rk[t] = ko; }
            }
            __syncthreads();
        }
        if (t == 0) bk_lds[pl] = rk[0];        // exact index replaces approx
        __syncthreads();
    }

    // single STE write phase: 128 positions x 64 channels
    const int pl = t & 127;
    const int half = t >> 7;
    const int bk = bk_lds[pl];
    const int sp = sp0 + pl;
    const float* xb = x + (size_t)b * XSTRIDE + sp;
    float* ob = out + (size_t)b * XSTRIDE + sp;
#pragma unroll
    for (int i = 0; i < 32; ++i) {
        const int c = half * 32 + i;
        const float xq = xb[(size_t)c * HW];
        const float qv = e[c * K + bk];
        ob[(size_t)c * HW] = xq + (qv - xq);   // np STE: fl(x + fl(q-x))
    }
}

extern "C" void kernel_launch(void* const* d_in, const int* in_sizes, int n_in,
                              void* d_out, int out_size, void* d_ws, size_t ws_size,
                              hipStream_t stream) {
    const float* x = (const float*)d_in[0];
    const float* e = (const float*)d_in[1];
    float* out = (float*)d_out;

    char* ws = (char*)d_ws;                          // ~260 KB used
    unsigned short* ebf = (unsigned short*)ws;       // 256 KB B-fragments
    float* c2n = (float*)(ws + 262144);              // 4 KB  (-0.5*sum e^2)

    vq_prep<<<64, 256, 0, stream>>>(e, ebf, c2n);
    vq_main<<<NPOS / 128, 256, 0, stream>>>(x, e, ebf, c2n, out);
}

// Round 7
// 125.815 us; speedup vs baseline: 1.0519x; 1.0257x over previous
//
#include <hip/hip_runtime.h>

// VQ: x (16,64,64,64) f32, codebook e (64,1024) f32. N=65536, D=64, K=1024.
//
// R13: R12 post-mortem: resolve cost is ~16us because it is BLOCK-SERIAL
// (~4 items/block, each a full 256-thread scan with ~10 barriers). The
// occupancy theory was wrong (VGPR 128->60 moved dur only 72.6->68.8).
// Fix: per-WAVE resolve, zero barriers:
//  - items dealt i = w, w+4, ... (one position per wave, 4-way parallel);
//  - R9's shfl-broadcast math, PROVEN bit-exact over all 65536 positions
//    (R9's fallback produced the entire output, absmax 0.0): lane holds
//    channel d=lane, __shfl broadcasts; 16 codes/lane (k=lane*16+m),
//    sequential-d FMA chain per code, pairwise-8 Ap, lane-major butterfly
//    argmin with ascending-k tie-breaks == np.argmin scan order;
//  - each wave writes its own bk_lds[pl] (disjoint) -> no sync until the
//    single __syncthreads before the STE write phase;
//  - rs/rk/xlds LDS arrays deleted; resolve d-unroll capped at 4 (VGPR).
// Tile loop / certify / write: R10-verbatim (register-staged LDS double
// buffer, 3-term split-bf16, m = x.e - 0.5*c2 via acc-init, argMAX,
// certify iff m1-m2 > MARGIN/2). Proven absmax 0.

#define D 64
#define K 1024
#define NPOS 65536
#define HW 4096
#define XSTRIDE 262144  // D*HW
#define MARGIN 1.0e-3f

typedef float vfloat4 __attribute__((ext_vector_type(4)));
typedef short short8  __attribute__((ext_vector_type(8)));

static __device__ __forceinline__ unsigned short bf16_rne(float f) {
    unsigned u = __float_as_uint(f);
    u += 0x7FFFu + ((u >> 16) & 1u);
    return (unsigned short)(u >> 16);
}
static __device__ __forceinline__ float bf16_to_f32(unsigned short h) {
    return __uint_as_float(((unsigned)h) << 16);
}

// ---- prep: codebook -> bf16 split B-fragments + c2n = -0.5*sum(e^2) -------
// frag layout: ebf[tile][s][split][lane][j], lane=q*16+n, value =
// split(e[d][k]), d=s*32+q*8+j, k=tile*16+n. Thread t of the main kernel
// owns 16B at t*16 within a tile: stage load + ds_write are linear copies.
__global__ void vq_prep(const float* __restrict__ e,
                        unsigned short* __restrict__ ebf,
                        float* __restrict__ c2n) {
    const int tile = blockIdx.x;               // 0..63
    const int t = threadIdx.x;
    const int n = t & 15;
    const int dg = t >> 4;                     // 0..15
#pragma unroll
    for (int i = 0; i < 4; ++i) {
        const int d = dg * 4 + i;
        const float v = e[d * K + tile * 16 + n];
        const unsigned short hh = bf16_rne(v);
        const float rem = v - bf16_to_f32(hh);     // exact (Sterbenz)
        const unsigned short hl = bf16_rne(rem);
        const int s = d >> 5, q = (d >> 3) & 3, j = d & 7;
        const int lanei = q * 16 + n;
        ebf[(((tile * 2 + s) * 2 + 0) * 64 + lanei) * 8 + j] = hh;
        ebf[(((tile * 2 + s) * 2 + 1) * 64 + lanei) * 8 + j] = hl;
    }
    if (t < 16) {
        const int k = tile * 16 + t;
        float s = 0.f;
#pragma unroll
        for (int d = 0; d < D; ++d) {
            const float v = e[d * K + k];      // sequential-d rounded squares
            s = s + __fmul_rn(v, v);
        }
        c2n[k] = -0.5f * s;
    }
}

// ---- main: 512 blocks x 256 threads; block = 128 positions, 4 waves -------
// Tile loop + certify as R10; per-wave exact resolve; one STE write phase.
__global__ __launch_bounds__(256, 2)
void vq_main(const float* __restrict__ x, const float* __restrict__ e,
             const unsigned short* __restrict__ ebf,
             const float* __restrict__ c2n,
             float* __restrict__ out) {
    __shared__ __align__(16) unsigned short lds_e[2][2048];  // 2 x 4 KB tiles
    __shared__ int   bk_lds[128];
    __shared__ int   lwl[128];
    __shared__ int   lwl_count;
    const int t = threadIdx.x;
    const int lane = t & 63;
    const int w = t >> 6;                      // wave 0..3 = position group
    const int p0 = blockIdx.x * 128;
    const int b = p0 >> 12;                    // 128 | 4096 -> single b
    const int sp0 = p0 & (HW - 1);
    const int n = lane & 15;                   // A-row m / B-col n / C col
    const int q = lane >> 4;                   // k-quad / C row group

    if (t == 0) lwl_count = 0;

    // A-frags (registers): xh/xl for 2 M-tiles x 2 K-steps
    short8 ah[2][2], al[2][2];
#pragma unroll
    for (int mt = 0; mt < 2; ++mt) {
        const int spc = sp0 + w * 32 + mt * 16 + n;
#pragma unroll
        for (int s = 0; s < 2; ++s) {
            short8 fh, fl_;
#pragma unroll
            for (int j = 0; j < 8; ++j) {
                const int d = s * 32 + q * 8 + j;      // A[m=n][k=q*8+j]
                const float v = x[(size_t)b * XSTRIDE + (size_t)d * HW + spc];
                const unsigned short h = bf16_rne(v);
                fh[j] = (short)h;
                fl_[j] = (short)bf16_rne(v - bf16_to_f32(h));
            }
            ah[mt][s] = fh; al[mt][s] = fl_;
        }
    }

    // stage tile 0: global -> reg -> LDS (thread t owns 16B at t*16)
    {
        const short8 stg = *(const short8*)(ebf + t * 8);
        *(short8*)(&lds_e[0][t * 8]) = stg;
    }

    float s1[2][4], s2[2][4]; int t1[2][4];
#pragma unroll
    for (int mt = 0; mt < 2; ++mt)
#pragma unroll
        for (int r = 0; r < 4; ++r) { s1[mt][r] = -3.4e38f; s2[mt][r] = -3.4e38f; t1[mt][r] = 0; }

    __syncthreads();                           // tile 0 in LDS + lwl_count=0

    for (int tt = 0; tt < 64; ++tt) {
        const int cur = tt & 1;
        short8 stg;
        if (tt < 63)                           // issue early: hide L2 latency
            stg = *(const short8*)(ebf + (size_t)(tt + 1) * 2048 + t * 8);
        const short8* fb = (const short8*)(&lds_e[cur][0]);
        const short8 bh0 = fb[lane];           // s0 hi
        const short8 bl0 = fb[64 + lane];      // s0 lo
        const short8 bh1 = fb[128 + lane];     // s1 hi
        const short8 bl1 = fb[192 + lane];     // s1 lo
        const float c2v = c2n[tt * 16 + n];
#pragma unroll
        for (int mt = 0; mt < 2; ++mt) {
            vfloat4 acc = {c2v, c2v, c2v, c2v};    // m = x.e - 0.5*c2
            acc = __builtin_amdgcn_mfma_f32_16x16x32_bf16(ah[mt][0], bh0, acc, 0, 0, 0);
            acc = __builtin_amdgcn_mfma_f32_16x16x32_bf16(ah[mt][1], bh1, acc, 0, 0, 0);
            acc = __builtin_amdgcn_mfma_f32_16x16x32_bf16(al[mt][0], bh0, acc, 0, 0, 0);
            acc = __builtin_amdgcn_mfma_f32_16x16x32_bf16(al[mt][1], bh1, acc, 0, 0, 0);
            acc = __builtin_amdgcn_mfma_f32_16x16x32_bf16(ah[mt][0], bl0, acc, 0, 0, 0);
            acc = __builtin_amdgcn_mfma_f32_16x16x32_bf16(ah[mt][1], bl1, acc, 0, 0, 0);
#pragma unroll
            for (int r = 0; r < 4; ++r) {      // C/D: row=q*4+r, col=n; argMAX
                const float m = acc[r];
                const bool gt = m > s1[mt][r];
                s2[mt][r] = fmaxf(s2[mt][r], fminf(m, s1[mt][r]));
                s1[mt][r] = gt ? m : s1[mt][r];
                t1[mt][r] = gt ? tt : t1[mt][r];
            }
        }
        if (tt < 63)                           // reg dep forces vmcnt wait
            *(short8*)(&lds_e[cur ^ 1][t * 8]) = stg;
        __syncthreads();                       // ds_write visible to all waves
    }

    // merge top-2 across the 16 code-columns; certify; push LOCAL worklist
#pragma unroll
    for (int mt = 0; mt < 2; ++mt)
#pragma unroll
        for (int r = 0; r < 4; ++r) {
            float a1 = s1[mt][r], a2 = s2[mt][r];
            int ak = t1[mt][r] * 16 + n;
#pragma unroll
            for (int m = 1; m < 16; m <<= 1) {
                const float o1 = __shfl_xor(a1, m, 64);
                const float o2 = __shfl_xor(a2, m, 64);
                const int   ok = __shfl_xor(ak, m, 64);
                const bool take = (o1 > a1) || (o1 == a1 && ok < ak);
                const float loser = take ? a1 : o1;
                a1 = take ? o1 : a1;
                ak = take ? ok : ak;
                a2 = fmaxf(fmaxf(a2, o2), loser);
            }
            if (n == 0) {
                const int pl = w * 32 + mt * 16 + q * 4 + r;
                bk_lds[pl] = ak;
                if (a1 - a2 <= 0.5f * MARGIN) {   // score gap = 2*(m1-m2)
                    const int idx = atomicAdd(&lwl_count, 1);
                    lwl[idx] = pl;
                }
            }
        }
    __syncthreads();

    // per-WAVE exact resolve (R9-verified shfl-broadcast bit-exact np scan):
    // one ambiguous position per wave, no barriers, disjoint bk_lds writes.
    const int cnt = lwl_count;                 // uniform after barrier
    for (int i = w; i < cnt; i += 4) {
        const int pl = lwl[i];
        const int sp = sp0 + pl;
        // lane holds channel d=lane of this position; broadcast via shfl
        const float myx = x[(size_t)b * XSTRIDE + (size_t)lane * HW + sp];
        // Ap = np.sum(x**2) in numpy pairwise-8 order (verified grouping)
        float r8[8];
#pragma unroll
        for (int i0 = 0; i0 < 8; ++i0) {
            const float v = __shfl(myx, i0, 64);
            r8[i0] = __fmul_rn(v, v);
        }
#pragma unroll
        for (int j = 1; j < 8; ++j)
#pragma unroll
            for (int i0 = 0; i0 < 8; ++i0) {
                const float v = __shfl(myx, 8 * j + i0, 64);
                r8[i0] = r8[i0] + __fmul_rn(v, v);
            }
        const float Ap = ((r8[0] + r8[1]) + (r8[2] + r8[3])) + ((r8[4] + r8[5]) + (r8[6] + r8[7]));
        // 16 codes per lane (k = lane*16+m); sequential-d FMA chain per code
        float acc[16];
#pragma unroll
        for (int m = 0; m < 16; ++m) acc[m] = 0.f;
#pragma unroll 4
        for (int d = 0; d < D; ++d) {
            const float xd = __shfl(myx, d, 64);
            const vfloat4 e0 = *(const vfloat4*)(e + d * K + lane * 16);
            const vfloat4 e1 = *(const vfloat4*)(e + d * K + lane * 16 + 4);
            const vfloat4 e2 = *(const vfloat4*)(e + d * K + lane * 16 + 8);
            const vfloat4 e3 = *(const vfloat4*)(e + d * K + lane * 16 + 12);
#pragma unroll
            for (int c = 0; c < 4; ++c) {
                acc[c]      = __builtin_fmaf(xd, e0[c], acc[c]);
                acc[4 + c]  = __builtin_fmaf(xd, e1[c], acc[4 + c]);
                acc[8 + c]  = __builtin_fmaf(xd, e2[c], acc[8 + c]);
                acc[12 + c] = __builtin_fmaf(xd, e3[c], acc[12 + c]);
            }
        }
        float bs = 3.4e38f; int bk = 0x7fffffff;
#pragma unroll
        for (int m = 0; m < 16; ++m) {
            const int k = lane * 16 + m;       // ascending k per lane
            const float c2k = -2.0f * c2n[k];  // exact pow2 scale = np c2[k]
            const float sc = __builtin_fmaf(-2.f, acc[m], Ap) + c2k;
            if (sc < bs || (sc == bs && k < bk)) { bs = sc; bk = k; }
        }
#pragma unroll
        for (int mm = 1; mm < 64; mm <<= 1) {  // lane-major k order = global
            const float os = __shfl_xor(bs, mm, 64);
            const int   ok = __shfl_xor(bk, mm, 64);
            if (os < bs || (os == bs && ok < bk)) { bs = os; bk = ok; }
        }
        if (lane == 0) bk_lds[pl] = bk;        // exact index replaces approx
    }
    __syncthreads();

    // single STE write phase: 128 positions x 64 channels
    const int pl = t & 127;
    const int half = t >> 7;
    const int bk = bk_lds[pl];
    const int sp = sp0 + pl;
    const float* xb = x + (size_t)b * XSTRIDE + sp;
    float* ob = out + (size_t)b * XSTRIDE + sp;
#pragma unroll
    for (int i = 0; i < 32; ++i) {
        const int c = half * 32 + i;
        const float xq = xb[(size_t)c * HW];
        const float qv = e[c * K + bk];
        ob[(size_t)c * HW] = xq + (qv - xq);   // np STE: fl(x + fl(q-x))
    }
}

extern "C" void kernel_launch(void* const* d_in, const int* in_sizes, int n_in,
                              void* d_out, int out_size, void* d_ws, size_t ws_size,
                              hipStream_t stream) {
    const float* x = (const float*)d_in[0];
    const float* e = (const float*)d_in[1];
    float* out = (float*)d_out;

    char* ws = (char*)d_ws;                          // ~260 KB used
    unsigned short* ebf = (unsigned short*)ws;       // 256 KB B-fragments
    float* c2n = (float*)(ws + 262144);              // 4 KB  (-0.5*sum e^2)

    vq_prep<<<64, 256, 0, stream>>>(e, ebf, c2n);
    vq_main<<<NPOS / 128, 256, 0, stream>>>(x, e, ebf, c2n, out);
}